// Round 5
// baseline (384.327 us; speedup 1.0000x reference)
//
#include <hip/hip_runtime.h>

#define Bb_ 4
#define Hh_ 16
#define Ss_ 1024
#define DH 64
#define MAXLEN 2048
#define BH (Bb_*Hh_)
#define LDST 72   // 64 + 8 pad (bf16 elems) -> 144B row stride, 16B aligned

typedef __attribute__((ext_vector_type(8))) short short8;
typedef __attribute__((ext_vector_type(4))) float floatx4;
typedef __attribute__((ext_vector_type(4))) unsigned short ushort4v;

static __device__ __forceinline__ unsigned short f2bf(float f) {
    unsigned int u = __builtin_bit_cast(unsigned int, f);
    u = (u + 0x7fffu + ((u >> 16) & 1u)) >> 16;   // RNE
    return (unsigned short)u;
}

// Stage a 128x64 fp32 tile (row stride 64) -> bf16 LDS tile (row stride LDST)
static __device__ __forceinline__ void stage_tile(unsigned short* lds,
                                                  const float* __restrict__ g,
                                                  int tid) {
#pragma unroll
    for (int it = 0; it < 8; ++it) {
        int idx = it * 1024 + tid * 4;
        int row = idx >> 6, col = idx & 63;
        const float4 v = *reinterpret_cast<const float4*>(g + row * 64 + col);
        ushort4v o = { f2bf(v.x), f2bf(v.y), f2bf(v.z), f2bf(v.w) };
        *reinterpret_cast<ushort4v*>(lds + row * LDST + col) = o;
    }
}

// ---- Kernel A: ctx = clip(sum_t sigmoid(qk/8)*t), then pemb[bh,t,:] bf16 ----
__global__ __launch_bounds__(256, 2)
void ctx_emb_kernel(const float* __restrict__ q, const float* __restrict__ k,
                    const float* __restrict__ tb,
                    unsigned short* __restrict__ pemb) {
    __shared__ __align__(16) unsigned short Ab[128 * LDST];
    __shared__ __align__(16) unsigned short Kb[128 * LDST];
    __shared__ float sh_ctx[128];

    int bx = blockIdx.x;
    int bh = bx >> 3, mt = bx & 7;
    int m0 = mt << 7;
    int tid = threadIdx.x;
    int lane = tid & 63, w = tid >> 6;
    int lo = lane & 15, quad = lane >> 4;

    stage_tile(Ab, q + (size_t)(bh * Ss_ + m0) * DH, tid);
    __syncthreads();

    short8 afr[2][2];
#pragma unroll
    for (int i = 0; i < 2; ++i)
#pragma unroll
        for (int k2 = 0; k2 < 2; ++k2)
            afr[i][k2] = *reinterpret_cast<const short8*>(
                &Ab[(w * 32 + i * 16 + lo) * LDST + k2 * 32 + quad * 8]);

    float rp[2][4];
#pragma unroll
    for (int i = 0; i < 2; ++i)
#pragma unroll
        for (int r = 0; r < 4; ++r) rp[i][r] = 0.f;

    for (int tt = 0; tt < 8; ++tt) {
        int t0 = tt << 7;
        __syncthreads();  // previous iter's Kb frag reads done
        stage_tile(Kb, k + (size_t)(bh * Ss_ + t0) * DH, tid);
        __syncthreads();

#pragma unroll
        for (int j = 0; j < 8; ++j) {
            short8 b0 = *reinterpret_cast<const short8*>(
                &Kb[(j * 16 + lo) * LDST + 0 + quad * 8]);
            short8 b1 = *reinterpret_cast<const short8*>(
                &Kb[(j * 16 + lo) * LDST + 32 + quad * 8]);
            float tcol = (float)(t0 + j * 16 + lo);
#pragma unroll
            for (int i = 0; i < 2; ++i) {
                floatx4 c = {0.f, 0.f, 0.f, 0.f};
                c = __builtin_amdgcn_mfma_f32_16x16x32_bf16(afr[i][0], b0, c, 0, 0, 0);
                c = __builtin_amdgcn_mfma_f32_16x16x32_bf16(afr[i][1], b1, c, 0, 0, 0);
#pragma unroll
                for (int r = 0; r < 4; ++r) {
                    float x = c[r] * 0.125f;
                    float e = __expf(-x);
                    float g = __builtin_amdgcn_rcpf(1.0f + e);
                    rp[i][r] += g * tcol;
                }
            }
        }
    }

#pragma unroll
    for (int i = 0; i < 2; ++i)
#pragma unroll
        for (int r = 0; r < 4; ++r) {
            float v = rp[i][r];
            v += __shfl_xor(v, 1);
            v += __shfl_xor(v, 2);
            v += __shfl_xor(v, 4);
            v += __shfl_xor(v, 8);
            rp[i][r] = v;
        }

    if (lo == 0) {
#pragma unroll
        for (int i = 0; i < 2; ++i)
#pragma unroll
            for (int r = 0; r < 4; ++r) {
                int row = w * 32 + i * 16 + quad * 4 + r;
                sh_ctx[row] = fminf(fmaxf(rp[i][r], 0.f), (float)(MAXLEN - 2));
            }
    }
    __syncthreads();

    // Interpolate pos_table at sh_ctx -> bf16 pemb[bh, m0+row, 0:64]
    {
        int rsub = tid >> 4;       // 0..15
        int d0 = (tid & 15) * 4;   // 0..60
#pragma unroll
        for (int pass = 0; pass < 8; ++pass) {
            int row = pass * 16 + rsub;
            float c = sh_ctx[row];
            int fl = (int)c;
            float fr = c - (float)fl;
            int ce = min(fl + 1, MAXLEN - 1);
            const float4 e0 = *reinterpret_cast<const float4*>(tb + fl * DH + d0);
            const float4 e1 = *reinterpret_cast<const float4*>(tb + ce * DH + d0);
            ushort4v o = { f2bf(e0.x + fr * (e1.x - e0.x)),
                           f2bf(e0.y + fr * (e1.y - e0.y)),
                           f2bf(e0.z + fr * (e1.z - e0.z)),
                           f2bf(e0.w + fr * (e1.w - e0.w)) };
            *reinterpret_cast<ushort4v*>(
                pemb + (size_t)(bh * Ss_ + m0 + row) * DH + d0) = o;
        }
    }
}

// ---- Kernel B: bias tile = Q . pemb^T, zero-LDS, no barriers ---------------
__global__ __launch_bounds__(256, 2)
void bias_kernel(const float* __restrict__ q,
                 const unsigned short* __restrict__ pemb,
                 float* __restrict__ out) {
    int bx = blockIdx.x;
    // swizzle: blocks sharing a q-tile are 512 apart -> same XCD (512 % 8 == 0)
    int nt = bx >> 9;
    int rest = bx & 511;
    int bh = rest >> 3, mt = rest & 7;
    int m0 = mt << 7, n0 = nt << 7;
    int tid = threadIdx.x;
    int lane = tid & 63, w = tid >> 6;
    int lo = lane & 15, quad = lane >> 4;

    // A-fragments: fp32 global -> bf16 registers, no LDS
    const float* qb = q + (size_t)(bh * Ss_ + m0) * DH;
    short8 afr[2][2];
#pragma unroll
    for (int i = 0; i < 2; ++i)
#pragma unroll
        for (int k2 = 0; k2 < 2; ++k2) {
            const float* ap = qb + (w * 32 + i * 16 + lo) * DH + k2 * 32 + quad * 8;
            const float4 a0 = *reinterpret_cast<const float4*>(ap);
            const float4 a1 = *reinterpret_cast<const float4*>(ap + 4);
            short8 f;
            f[0] = (short)f2bf(a0.x); f[1] = (short)f2bf(a0.y);
            f[2] = (short)f2bf(a0.z); f[3] = (short)f2bf(a0.w);
            f[4] = (short)f2bf(a1.x); f[5] = (short)f2bf(a1.y);
            f[6] = (short)f2bf(a1.z); f[7] = (short)f2bf(a1.w);
            afr[i][k2] = f;
        }

    const unsigned short* pb = pemb + (size_t)(bh * Ss_ + n0) * DH;

    floatx4 acc[2][8];
#pragma unroll
    for (int i = 0; i < 2; ++i)
#pragma unroll
        for (int j = 0; j < 8; ++j) acc[i][j] = (floatx4){0.f, 0.f, 0.f, 0.f};

#pragma unroll
    for (int j = 0; j < 8; ++j) {
        const unsigned short* bp = pb + (j * 16 + lo) * DH + quad * 8;
        short8 b0 = *reinterpret_cast<const short8*>(bp);
        short8 b1 = *reinterpret_cast<const short8*>(bp + 32);
#pragma unroll
        for (int i = 0; i < 2; ++i) {
            acc[i][j] = __builtin_amdgcn_mfma_f32_16x16x32_bf16(afr[i][0], b0, acc[i][j], 0, 0, 0);
            acc[i][j] = __builtin_amdgcn_mfma_f32_16x16x32_bf16(afr[i][1], b1, acc[i][j], 0, 0, 0);
        }
    }

    float* outb = out + (size_t)(bh * Ss_ + m0) * Ss_ + n0;
#pragma unroll
    for (int i = 0; i < 2; ++i)
#pragma unroll
        for (int j = 0; j < 8; ++j)
#pragma unroll
            for (int r = 0; r < 4; ++r) {
                int row = w * 32 + i * 16 + quad * 4 + r;
                int col = j * 16 + lo;
                __builtin_nontemporal_store(
                    acc[i][j][r], outb + (size_t)row * Ss_ + col);
            }
}

extern "C" void kernel_launch(void* const* d_in, const int* in_sizes, int n_in,
                              void* d_out, int out_size, void* d_ws, size_t ws_size,
                              hipStream_t stream) {
    const float* q  = (const float*)d_in[0];
    const float* k  = (const float*)d_in[1];
    const float* tb = (const float*)d_in[2];
    unsigned short* pemb = (unsigned short*)d_ws;   // BH*S*64 bf16 = 8 MB
    float* out = (float*)d_out;

    ctx_emb_kernel<<<BH * 8, 256, 0, stream>>>(q, k, tb, pemb);
    bias_kernel<<<BH * 64, 256, 0, stream>>>(q, pemb, out);
}

// Round 6
// 351.364 us; speedup vs baseline: 1.0938x; 1.0938x over previous
//
#include <hip/hip_runtime.h>

#define Bb_ 4
#define Hh_ 16
#define Ss_ 1024
#define DH 64
#define MAXLEN 2048
#define BH (Bb_*Hh_)
#define LDST 72   // 64 + 8 pad (bf16 elems) -> 144B row stride, 16B aligned

typedef __attribute__((ext_vector_type(8))) short short8;
typedef __attribute__((ext_vector_type(4))) float floatx4;
typedef __attribute__((ext_vector_type(4))) unsigned short ushort4v;

static __device__ __forceinline__ unsigned short f2bf(float f) {
    unsigned int u = __builtin_bit_cast(unsigned int, f);
    u = (u + 0x7fffu + ((u >> 16) & 1u)) >> 16;   // RNE
    return (unsigned short)u;
}

// Stage a 128x64 fp32 tile (row stride 64) -> bf16 LDS tile (row stride LDST)
static __device__ __forceinline__ void stage_tile(unsigned short* lds,
                                                  const float* __restrict__ g,
                                                  int tid) {
#pragma unroll
    for (int it = 0; it < 8; ++it) {
        int idx = it * 1024 + tid * 4;
        int row = idx >> 6, col = idx & 63;
        const float4 v = *reinterpret_cast<const float4*>(g + row * 64 + col);
        ushort4v o = { f2bf(v.x), f2bf(v.y), f2bf(v.z), f2bf(v.w) };
        *reinterpret_cast<ushort4v*>(lds + row * LDST + col) = o;
    }
}

// ---------------- Kernel A: ctx_pos = clip(sum_t sigmoid(qk/8)*t, 0, 2046) ----
__global__ __launch_bounds__(256, 2)
void ctx_kernel(const float* __restrict__ q, const float* __restrict__ k,
                float* __restrict__ ctx) {
    __shared__ __align__(16) unsigned short Ab[128 * LDST];
    __shared__ __align__(16) unsigned short Kb[128 * LDST];

    int bx = blockIdx.x;
    int bh = bx >> 3, mt = bx & 7;
    int m0 = mt << 7;
    int tid = threadIdx.x;
    int lane = tid & 63, w = tid >> 6;
    int lo = lane & 15, quad = lane >> 4;

    stage_tile(Ab, q + (size_t)(bh * Ss_ + m0) * DH, tid);
    __syncthreads();

    short8 afr[2][2];
#pragma unroll
    for (int i = 0; i < 2; ++i)
#pragma unroll
        for (int k2 = 0; k2 < 2; ++k2)
            afr[i][k2] = *reinterpret_cast<const short8*>(
                &Ab[(w * 32 + i * 16 + lo) * LDST + k2 * 32 + quad * 8]);

    float rp[2][4];
#pragma unroll
    for (int i = 0; i < 2; ++i)
#pragma unroll
        for (int r = 0; r < 4; ++r) rp[i][r] = 0.f;

    for (int tt = 0; tt < 8; ++tt) {
        int t0 = tt << 7;
        __syncthreads();  // previous iter's Kb frag reads done
        stage_tile(Kb, k + (size_t)(bh * Ss_ + t0) * DH, tid);
        __syncthreads();

#pragma unroll
        for (int j = 0; j < 8; ++j) {
            short8 b0 = *reinterpret_cast<const short8*>(
                &Kb[(j * 16 + lo) * LDST + 0 + quad * 8]);
            short8 b1 = *reinterpret_cast<const short8*>(
                &Kb[(j * 16 + lo) * LDST + 32 + quad * 8]);
            float tcol = (float)(t0 + j * 16 + lo);
#pragma unroll
            for (int i = 0; i < 2; ++i) {
                floatx4 c = {0.f, 0.f, 0.f, 0.f};
                c = __builtin_amdgcn_mfma_f32_16x16x32_bf16(afr[i][0], b0, c, 0, 0, 0);
                c = __builtin_amdgcn_mfma_f32_16x16x32_bf16(afr[i][1], b1, c, 0, 0, 0);
#pragma unroll
                for (int r = 0; r < 4; ++r) {
                    float x = c[r] * 0.125f;
                    float e = __expf(-x);
                    float g = __builtin_amdgcn_rcpf(1.0f + e);
                    rp[i][r] += g * tcol;
                }
            }
        }
    }

    // reduce across the 16 lanes (cols) sharing each row
#pragma unroll
    for (int i = 0; i < 2; ++i)
#pragma unroll
        for (int r = 0; r < 4; ++r) {
            float v = rp[i][r];
            v += __shfl_xor(v, 1);
            v += __shfl_xor(v, 2);
            v += __shfl_xor(v, 4);
            v += __shfl_xor(v, 8);
            rp[i][r] = v;
        }

    if (lo == 0) {
#pragma unroll
        for (int i = 0; i < 2; ++i)
#pragma unroll
            for (int r = 0; r < 4; ++r) {
                int row = m0 + w * 32 + i * 16 + quad * 4 + r;
                float v = fminf(fmaxf(rp[i][r], 0.f), (float)(MAXLEN - 2));
                ctx[bh * Ss_ + row] = v;
            }
    }
}

// ---------------- Kernel B: bias = Q . pos_emb^T  (K = 64) -------------------
// R3 structure (LDS-staged A and B fragments) + 4 blocks/CU + direct NT stores.
__global__ __launch_bounds__(256, 4)
void bias_kernel(const float* __restrict__ q, const float* __restrict__ tb,
                 const float* __restrict__ ctx, float* __restrict__ out) {
    __shared__ __align__(16) unsigned short Ab[128 * LDST];
    __shared__ __align__(16) unsigned short Pb[128 * LDST];

    int bx = blockIdx.x;
    int bh = bx >> 6;
    int mt = (bx >> 3) & 7;
    int nt = bx & 7;
    int m0 = mt << 7, n0 = nt << 7;
    int tid = threadIdx.x;
    int lane = tid & 63, w = tid >> 6;
    int lo = lane & 15, quad = lane >> 4;

    stage_tile(Ab, q + (size_t)(bh * Ss_ + m0) * DH, tid);

    // Build interpolated pos_emb tile (128 t-rows x 64 d) in bf16
    {
        int rsub = tid >> 4;       // 0..15
        int d0 = (tid & 15) * 4;   // 0..60
#pragma unroll
        for (int pass = 0; pass < 8; ++pass) {
            int row = pass * 16 + rsub;
            float c = ctx[bh * Ss_ + n0 + row];
            int fl = (int)c;
            float fr = c - (float)fl;
            int ce = min(fl + 1, MAXLEN - 1);
            const float4 e0 = *reinterpret_cast<const float4*>(tb + fl * DH + d0);
            const float4 e1 = *reinterpret_cast<const float4*>(tb + ce * DH + d0);
            ushort4v o = { f2bf(e0.x + fr * (e1.x - e0.x)),
                           f2bf(e0.y + fr * (e1.y - e0.y)),
                           f2bf(e0.z + fr * (e1.z - e0.z)),
                           f2bf(e0.w + fr * (e1.w - e0.w)) };
            *reinterpret_cast<ushort4v*>(&Pb[row * LDST + d0]) = o;
        }
    }
    __syncthreads();

    short8 afr[2][2];
#pragma unroll
    for (int i = 0; i < 2; ++i)
#pragma unroll
        for (int k2 = 0; k2 < 2; ++k2)
            afr[i][k2] = *reinterpret_cast<const short8*>(
                &Ab[(w * 32 + i * 16 + lo) * LDST + k2 * 32 + quad * 8]);

    floatx4 acc[2][8];
#pragma unroll
    for (int i = 0; i < 2; ++i)
#pragma unroll
        for (int j = 0; j < 8; ++j) acc[i][j] = (floatx4){0.f, 0.f, 0.f, 0.f};

#pragma unroll
    for (int j = 0; j < 8; ++j) {
        short8 b0 = *reinterpret_cast<const short8*>(
            &Pb[(j * 16 + lo) * LDST + 0 + quad * 8]);
        short8 b1 = *reinterpret_cast<const short8*>(
            &Pb[(j * 16 + lo) * LDST + 32 + quad * 8]);
#pragma unroll
        for (int i = 0; i < 2; ++i) {
            acc[i][j] = __builtin_amdgcn_mfma_f32_16x16x32_bf16(afr[i][0], b0, acc[i][j], 0, 0, 0);
            acc[i][j] = __builtin_amdgcn_mfma_f32_16x16x32_bf16(afr[i][1], b1, acc[i][j], 0, 0, 0);
        }
    }

    // Direct NT scalar stores (j-unroll covers full lines within the burst)
#pragma unroll
    for (int i = 0; i < 2; ++i)
#pragma unroll
        for (int j = 0; j < 8; ++j)
#pragma unroll
            for (int r = 0; r < 4; ++r) {
                int row = w * 32 + i * 16 + quad * 4 + r;
                int col = j * 16 + lo;
                __builtin_nontemporal_store(
                    acc[i][j][r],
                    out + (size_t)(bh * Ss_ + m0 + row) * Ss_ + n0 + col);
            }
}

extern "C" void kernel_launch(void* const* d_in, const int* in_sizes, int n_in,
                              void* d_out, int out_size, void* d_ws, size_t ws_size,
                              hipStream_t stream) {
    const float* q  = (const float*)d_in[0];
    const float* k  = (const float*)d_in[1];
    const float* tb = (const float*)d_in[2];
    float* ctx = (float*)d_ws;          // BH*S floats = 256 KB
    float* out = (float*)d_out;

    ctx_kernel<<<BH * 8, 256, 0, stream>>>(q, k, ctx);
    bias_kernel<<<BH * 64, 256, 0, stream>>>(q, tb, ctx, out);
}

// Round 7
// 323.554 us; speedup vs baseline: 1.1878x; 1.0860x over previous
//
#include <hip/hip_runtime.h>

#define Bb_ 4
#define Hh_ 16
#define Ss_ 1024
#define DH 64
#define MAXLEN 2048
#define BH (Bb_*Hh_)
#define LDST 72   // 64 + 8 pad (bf16 elems) -> 144B row stride, 16B aligned
#define SW 132    // fp32 epilogue scratch stride (128 + 4 pad words)

typedef __attribute__((ext_vector_type(8))) short short8;
typedef __attribute__((ext_vector_type(4))) float floatx4;
typedef __attribute__((ext_vector_type(4))) unsigned short ushort4v;

static __device__ __forceinline__ unsigned short f2bf(float f) {
    unsigned int u = __builtin_bit_cast(unsigned int, f);
    u = (u + 0x7fffu + ((u >> 16) & 1u)) >> 16;   // RNE
    return (unsigned short)u;
}

// Stage a 128x64 fp32 tile (row stride 64) -> bf16 LDS tile (row stride LDST)
static __device__ __forceinline__ void stage_tile(unsigned short* lds,
                                                  const float* __restrict__ g,
                                                  int tid) {
#pragma unroll
    for (int it = 0; it < 8; ++it) {
        int idx = it * 1024 + tid * 4;
        int row = idx >> 6, col = idx & 63;
        const float4 v = *reinterpret_cast<const float4*>(g + row * 64 + col);
        ushort4v o = { f2bf(v.x), f2bf(v.y), f2bf(v.z), f2bf(v.w) };
        *reinterpret_cast<ushort4v*>(lds + row * LDST + col) = o;
    }
}

// ---------------- Kernel A: ctx_pos = clip(sum_t sigmoid(qk/8)*t, 0, 2046) ----
__global__ __launch_bounds__(256, 2)
void ctx_kernel(const float* __restrict__ q, const float* __restrict__ k,
                float* __restrict__ ctx) {
    __shared__ __align__(16) unsigned short Ab[128 * LDST];
    __shared__ __align__(16) unsigned short Kb[128 * LDST];

    int bx = blockIdx.x;
    int bh = bx >> 3, mt = bx & 7;
    int m0 = mt << 7;
    int tid = threadIdx.x;
    int lane = tid & 63, w = tid >> 6;
    int lo = lane & 15, quad = lane >> 4;

    stage_tile(Ab, q + (size_t)(bh * Ss_ + m0) * DH, tid);
    __syncthreads();

    short8 afr[2][2];
#pragma unroll
    for (int i = 0; i < 2; ++i)
#pragma unroll
        for (int k2 = 0; k2 < 2; ++k2)
            afr[i][k2] = *reinterpret_cast<const short8*>(
                &Ab[(w * 32 + i * 16 + lo) * LDST + k2 * 32 + quad * 8]);

    float rp[2][4];
#pragma unroll
    for (int i = 0; i < 2; ++i)
#pragma unroll
        for (int r = 0; r < 4; ++r) rp[i][r] = 0.f;

    for (int tt = 0; tt < 8; ++tt) {
        int t0 = tt << 7;
        __syncthreads();  // previous iter's Kb frag reads done
        stage_tile(Kb, k + (size_t)(bh * Ss_ + t0) * DH, tid);
        __syncthreads();

#pragma unroll
        for (int j = 0; j < 8; ++j) {
            short8 b0 = *reinterpret_cast<const short8*>(
                &Kb[(j * 16 + lo) * LDST + 0 + quad * 8]);
            short8 b1 = *reinterpret_cast<const short8*>(
                &Kb[(j * 16 + lo) * LDST + 32 + quad * 8]);
            float tcol = (float)(t0 + j * 16 + lo);
#pragma unroll
            for (int i = 0; i < 2; ++i) {
                floatx4 c = {0.f, 0.f, 0.f, 0.f};
                c = __builtin_amdgcn_mfma_f32_16x16x32_bf16(afr[i][0], b0, c, 0, 0, 0);
                c = __builtin_amdgcn_mfma_f32_16x16x32_bf16(afr[i][1], b1, c, 0, 0, 0);
#pragma unroll
                for (int r = 0; r < 4; ++r) {
                    float x = c[r] * 0.125f;
                    float e = __expf(-x);
                    float g = __builtin_amdgcn_rcpf(1.0f + e);
                    rp[i][r] += g * tcol;
                }
            }
        }
    }

    // reduce across the 16 lanes (cols) sharing each row
#pragma unroll
    for (int i = 0; i < 2; ++i)
#pragma unroll
        for (int r = 0; r < 4; ++r) {
            float v = rp[i][r];
            v += __shfl_xor(v, 1);
            v += __shfl_xor(v, 2);
            v += __shfl_xor(v, 4);
            v += __shfl_xor(v, 8);
            rp[i][r] = v;
        }

    if (lo == 0) {
#pragma unroll
        for (int i = 0; i < 2; ++i)
#pragma unroll
            for (int r = 0; r < 4; ++r) {
                int row = m0 + w * 32 + i * 16 + quad * 4 + r;
                float v = fminf(fmaxf(rp[i][r], 0.f), (float)(MAXLEN - 2));
                ctx[bh * Ss_ + row] = v;
            }
    }
}

// ---------------- Kernel B: bias = Q . pos_emb^T  (K = 64) -------------------
// R3 structure exactly; single change: 4 blocks/CU (LDS 4x36.9KB = 147.5 <= 160)
__global__ __launch_bounds__(256, 4)
void bias_kernel(const float* __restrict__ q, const float* __restrict__ tb,
                 const float* __restrict__ ctx, float* __restrict__ out) {
    // Union: staging (2 x 128*LDST ushorts = 36864 B) vs fp32 epilogue
    // scratch (64*SW*4 = 33792 B)
    __shared__ __align__(16) unsigned char smem[2 * 128 * LDST * 2];
    unsigned short* Ab = reinterpret_cast<unsigned short*>(smem);
    unsigned short* Pb = Ab + 128 * LDST;
    float* scratch = reinterpret_cast<float*>(smem);

    int bx = blockIdx.x;
    int bh = bx >> 6;
    int mt = (bx >> 3) & 7;
    int nt = bx & 7;
    int m0 = mt << 7, n0 = nt << 7;
    int tid = threadIdx.x;
    int lane = tid & 63, w = tid >> 6;
    int lo = lane & 15, quad = lane >> 4;

    stage_tile(Ab, q + (size_t)(bh * Ss_ + m0) * DH, tid);

    // Build interpolated pos_emb tile (128 t-rows x 64 d) in bf16
    {
        int rsub = tid >> 4;       // 0..15
        int d0 = (tid & 15) * 4;   // 0..60
#pragma unroll
        for (int pass = 0; pass < 8; ++pass) {
            int row = pass * 16 + rsub;
            float c = ctx[bh * Ss_ + n0 + row];
            int fl = (int)c;
            float fr = c - (float)fl;
            int ce = min(fl + 1, MAXLEN - 1);
            const float4 e0 = *reinterpret_cast<const float4*>(tb + fl * DH + d0);
            const float4 e1 = *reinterpret_cast<const float4*>(tb + ce * DH + d0);
            ushort4v o = { f2bf(e0.x + fr * (e1.x - e0.x)),
                           f2bf(e0.y + fr * (e1.y - e0.y)),
                           f2bf(e0.z + fr * (e1.z - e0.z)),
                           f2bf(e0.w + fr * (e1.w - e0.w)) };
            *reinterpret_cast<ushort4v*>(&Pb[row * LDST + d0]) = o;
        }
    }
    __syncthreads();

    short8 afr[2][2];
#pragma unroll
    for (int i = 0; i < 2; ++i)
#pragma unroll
        for (int k2 = 0; k2 < 2; ++k2)
            afr[i][k2] = *reinterpret_cast<const short8*>(
                &Ab[(w * 32 + i * 16 + lo) * LDST + k2 * 32 + quad * 8]);

    floatx4 acc[2][8];
#pragma unroll
    for (int i = 0; i < 2; ++i)
#pragma unroll
        for (int j = 0; j < 8; ++j) acc[i][j] = (floatx4){0.f, 0.f, 0.f, 0.f};

#pragma unroll
    for (int j = 0; j < 8; ++j) {
        short8 b0 = *reinterpret_cast<const short8*>(
            &Pb[(j * 16 + lo) * LDST + 0 + quad * 8]);
        short8 b1 = *reinterpret_cast<const short8*>(
            &Pb[(j * 16 + lo) * LDST + 32 + quad * 8]);
#pragma unroll
        for (int i = 0; i < 2; ++i) {
            acc[i][j] = __builtin_amdgcn_mfma_f32_16x16x32_bf16(afr[i][0], b0, acc[i][j], 0, 0, 0);
            acc[i][j] = __builtin_amdgcn_mfma_f32_16x16x32_bf16(afr[i][1], b1, acc[i][j], 0, 0, 0);
        }
    }

    // Epilogue: LDS transpose -> contiguous dwordx4 nontemporal stores.
    // Phase i handles 64 rows (16 per wave): global row = m0 + w*32 + i*16 + (lrow&15)
#pragma unroll
    for (int i = 0; i < 2; ++i) {
        __syncthreads();  // staging reads (i=0) / previous-phase reads (i=1) done
#pragma unroll
        for (int j = 0; j < 8; ++j)
#pragma unroll
            for (int r = 0; r < 4; ++r) {
                int lrow = w * 16 + quad * 4 + r;
                scratch[lrow * SW + j * 16 + lo] = acc[i][j][r];
            }
        __syncthreads();
#pragma unroll
        for (int it = 0; it < 8; ++it) {
            int flat = it * 1024 + tid * 4;
            int lrow = flat >> 7, col = flat & 127;
            floatx4 v = *reinterpret_cast<const floatx4*>(&scratch[lrow * SW + col]);
            int grow = m0 + (lrow >> 4) * 32 + i * 16 + (lrow & 15);
            __builtin_nontemporal_store(
                v, reinterpret_cast<floatx4*>(
                       out + (size_t)(bh * Ss_ + grow) * Ss_ + n0 + col));
        }
    }
}

extern "C" void kernel_launch(void* const* d_in, const int* in_sizes, int n_in,
                              void* d_out, int out_size, void* d_ws, size_t ws_size,
                              hipStream_t stream) {
    const float* q  = (const float*)d_in[0];
    const float* k  = (const float*)d_in[1];
    const float* tb = (const float*)d_in[2];
    float* ctx = (float*)d_ws;          // BH*S floats = 256 KB
    float* out = (float*)d_out;

    ctx_kernel<<<BH * 8, 256, 0, stream>>>(q, k, ctx);
    bias_kernel<<<BH * 64, 256, 0, stream>>>(q, tb, ctx, out);
}